// Round 5
// baseline (6593.933 us; speedup 1.0000x reference)
//
#include <hip/hip_runtime.h>
#include <hip/hip_bf16.h>
#include <cstdint>

typedef unsigned short ushort_t;
typedef __attribute__((ext_vector_type(8))) short short8;
typedef __attribute__((ext_vector_type(4))) float floatx4;
typedef __attribute__((ext_vector_type(4))) ushort_t ushort4v;

#define DEVI __device__ __forceinline__

DEVI float b2f(ushort_t u){ union{unsigned int i; float f;} v; v.i = ((unsigned int)u)<<16; return v.f; }
DEVI ushort_t f2b(float f){ union{float f; unsigned int i;} v; v.f=f; unsigned int r = (v.i + 0x7FFFu + ((v.i>>16)&1u)) >> 16; return (ushort_t)r; }

DEVI float gelu_f(float t){
  float t3 = t*t*t;
  return 0.5f*t*(1.0f + tanhf(0.7978845608028654f*(t + 0.044715f*t3)));
}

#define GLD_LDS16(src, dst) \
  __builtin_amdgcn_global_load_lds((const __attribute__((address_space(1))) void*)(src), \
                                   (__attribute__((address_space(3))) void*)(dst), 16, 0, 0)

// raw barrier: does NOT drain vmcnt (unlike __syncthreads); "memory" clobber
// stops the compiler moving LDS/global ops across it.
#define BAR()    asm volatile("s_barrier" ::: "memory")
#define WAITV(n) asm volatile("s_waitcnt vmcnt(" #n ")" ::: "memory")

#define MFMA16(d, a, b) d = __builtin_amdgcn_mfma_f32_16x16x32_bf16(a, b, d, 0, 0, 0)

// ---------------------------------------------------------------------------
// 256x256 tile, BK=64, 8 waves, double-buffered LDS (128 KiB), 4 phases/K-tile.
// ROUND-5 CHANGE: one-phase-AHEAD ds_reads with full register rotation
// (af0/af1/bf0/bf1 all distinct regs -> no WAR), so lgkmcnt at each phase's
// MFMA head waits on reads issued a full phase earlier (hidden under the
// previous MFMA cluster + barriers). Only P0's 12 reads are exposed (once
// per K-tile, right after the boundary certification BAR). K-loop statically
// unrolled 2 K-tiles/iter so all LDS addresses are base + immediate.
//
// Phase map per K-tile (buf static):
//   P0 body: stage r3(t+1)->other buf; read af0[8], bf0[4]   (exposed)
//   P0 mfma: acc[*][0] += af0*bf0[0]; acc[*][1] += af0*bf0[1]
//   P1 body: read af1[8], bf1[0], bf1[1]                      (for P2)
//   P1 mfma: acc[*][2] += af0*bf0[2]; acc[*][3] += af0*bf0[3]
//   P2 body: read bf1[2], bf1[3]                               (for P3)
//   P2 mfma: acc[*][0] += af1*bf1[0]; acc[*][1] += af1*bf1[1]
//   P3 mfma: acc[*][2] += af1*bf1[2]; acc[*][3] += af1*bf1[3]
// Boundary after each K-tile t: stage r0-r2(t+2) into buf(t); WAITV(6); BAR
//   -> certifies ALL of t+1 (proof: 14 outstanding -> drain 8 oldest = t+1's
//   r0-r3 + nothing newer), never drains the pipe to 0 mid-loop.
// Staging safety: stages into buf(t) only issued after P3(t)'s closing BAR
// (all waves' lgkm reads of buf(t) drained before their last MFMA). r3(t+1)
// into the other buffer is safe any time during t.
// LDS layout + XOR granule swizzle + pre-swizzled global source: unchanged
// from the verified round-4 kernel (bank conflicts measured 0).
// Requires nkt even (K = 1024 or 4096 here).
// ---------------------------------------------------------------------------
template<int BUFOFF>
DEVI void ktile(const ushort_t* aB0, const ushort_t* aB1,
                const ushort_t* bB0, const ushort_t* bB1, floatx4 (&acc)[8][4])
{
  short8 af0[8], af1[8], bf0[4], bf1[4];
  // ---- P0 body: this tile's k-half-0 operands (exposed reads)
  #pragma unroll
  for (int mi = 0; mi < 8; mi++) af0[mi] = *(const short8*)(aB0 + BUFOFF + mi*1024);
  #pragma unroll
  for (int ni = 0; ni < 4; ni++) bf0[ni] = *(const short8*)(bB0 + BUFOFF + ni*1024);
  BAR();
  __builtin_amdgcn_s_setprio(1);
  #pragma unroll
  for (int mi = 0; mi < 8; mi++){ MFMA16(acc[mi][0], af0[mi], bf0[0]); MFMA16(acc[mi][1], af0[mi], bf0[1]); }
  __builtin_amdgcn_s_setprio(0);
  BAR();
  // ---- P1 body: prefetch k-half-1 A + first half of B (consumed in P2)
  #pragma unroll
  for (int mi = 0; mi < 8; mi++) af1[mi] = *(const short8*)(aB1 + BUFOFF + mi*1024);
  bf1[0] = *(const short8*)(bB1 + BUFOFF);
  bf1[1] = *(const short8*)(bB1 + BUFOFF + 1024);
  BAR();
  __builtin_amdgcn_s_setprio(1);
  #pragma unroll
  for (int mi = 0; mi < 8; mi++){ MFMA16(acc[mi][2], af0[mi], bf0[2]); MFMA16(acc[mi][3], af0[mi], bf0[3]); }
  __builtin_amdgcn_s_setprio(0);
  BAR();
  // ---- P2 body: prefetch rest of k-half-1 B (consumed in P3)
  bf1[2] = *(const short8*)(bB1 + BUFOFF + 2048);
  bf1[3] = *(const short8*)(bB1 + BUFOFF + 3072);
  BAR();
  __builtin_amdgcn_s_setprio(1);
  #pragma unroll
  for (int mi = 0; mi < 8; mi++){ MFMA16(acc[mi][0], af1[mi], bf1[0]); MFMA16(acc[mi][1], af1[mi], bf1[1]); }
  __builtin_amdgcn_s_setprio(0);
  BAR();
  // ---- P3: no body reads; P2's closing BAR serves as the opening barrier
  __builtin_amdgcn_s_setprio(1);
  #pragma unroll
  for (int mi = 0; mi < 8; mi++){ MFMA16(acc[mi][2], af1[mi], bf1[2]); MFMA16(acc[mi][3], af1[mi], bf1[3]); }
  __builtin_amdgcn_s_setprio(0);
  BAR();   // P3 closing barrier = pre-boundary: all waves done reading this buf
}

DEVI void gemm_core(const ushort_t* __restrict__ A, const ushort_t* __restrict__ Bt,
                    int K, int tileM, int tileN, floatx4 (&acc)[8][4])
{
  __shared__ alignas(16) ushort_t As[2][16384];
  __shared__ alignas(16) ushort_t Bs[2][16384];
  const int tid  = threadIdx.x;
  const int wave = tid >> 6, lane = tid & 63;
  const int quad = lane >> 4, l16 = lane & 15;
  const int wm = wave >> 2, wn = wave & 3;          // 2 x 4 wave grid, 128x64 out each

  // staging: thread c handles row rr=c>>3, stored granule gg=(c&7)^(rr&7)
  // (inverse of the read-side swizzle; global source pre-swizzled)
  const int rr = tid >> 3;
  const int gg = (tid & 7) ^ (rr & 7);
  const ushort_t* srcA = A  + (size_t)(tileM + rr) * K + gg * 8;
  const ushort_t* srcB = Bt + (size_t)(tileN + rr) * K + gg * 8;
  const size_t K64 = (size_t)K * 64;
  ushort_t* dstA = &As[0][0] + wave * 512;
  ushort_t* dstB = &Bs[0][0] + wave * 512;

#define STAGE2(sp, dp) do{ GLD_LDS16((sp), (dp)); GLD_LDS16((sp) + K64, (dp) + 4096); }while(0)

  // frag-read bases: slot swizzle s0 (k-half 0) and s0^32 (k-half 1)
  const int s0 = (quad ^ (l16 & 7)) * 8;
  const int s1 = s0 ^ 32;
  const ushort_t* aB0 = &As[0][0] + (wm*128 + l16)*64 + s0;
  const ushort_t* aB1 = &As[0][0] + (wm*128 + l16)*64 + s1;
  const ushort_t* bB0 = &Bs[0][0] + (wn*64  + l16)*64 + s0;
  const ushort_t* bB1 = &Bs[0][0] + (wn*64  + l16)*64 + s1;

  const int nkt = K >> 6;   // even for all K used here (16 or 64)

  // prologue: tile0 fully -> buf0; tile1 regions r0-r2 -> buf1; certify tile0
  STAGE2(srcA,              dstA);
  STAGE2(srcA + 2*K64,      dstA + 8192);
  STAGE2(srcB,              dstB);
  STAGE2(srcB + 2*K64,      dstB + 8192);
  if (nkt > 1){
    STAGE2(srcA + 64,          dstA + 16384);
    STAGE2(srcA + 64 + 2*K64,  dstA + 16384 + 8192);
    STAGE2(srcB + 64,          dstB + 16384);
    WAITV(6);
  } else {
    WAITV(0);
  }
  BAR();

  for (int tt = 0; tt < nkt; tt += 2){
    // P0 body of tile tt: stage r3(tt+1) into buf1 (other buffer - safe)
    STAGE2(srcB + (size_t)(tt+1)*64 + 2*K64, dstB + 16384 + 8192);
    ktile<0>(aB0, aB1, bB0, bB1, acc);
    // boundary after tile tt
    if (tt + 2 < nkt){
      const size_t k8 = (size_t)(tt+2) * 64;
      STAGE2(srcA + k8,          dstA);
      STAGE2(srcA + k8 + 2*K64,  dstA + 8192);
      STAGE2(srcB + k8,          dstB);
      WAITV(6); BAR();
      STAGE2(srcB + k8 + 2*K64,  dstB + 8192);   // r3(tt+2): P0 body of tile tt+1
    } else {
      WAITV(0); BAR();                            // certify last tile (tt+1)
    }
    ktile<16384>(aB0, aB1, bB0, bB1, acc);
    // boundary after tile tt+1
    if (tt + 3 < nkt){
      const size_t k8 = (size_t)(tt+3) * 64;
      STAGE2(srcA + k8,          dstA + 16384);
      STAGE2(srcA + k8 + 2*K64,  dstA + 16384 + 8192);
      STAGE2(srcB + k8,          dstB + 16384);
      WAITV(6); BAR();
    }
    // tt+3 >= nkt: last pair finished, fall out
  }
#undef STAGE2
}

// out[M,N](bf16) = epi(A[M,K](bf16) @ Bt[N,K]^T + bias(fp32) [, res(fp32)])
// EPI: 0 = elu(v)+1, 1 = v, 2 = gelu(v), 3 = gelu(v)+res
template<int EPI>
__global__ __launch_bounds__(512, 2)
void gemm_kernel(const ushort_t* __restrict__ A, const ushort_t* __restrict__ Bt,
                 const float* __restrict__ bias, const float* __restrict__ res,
                 ushort_t* __restrict__ out, int N, int K)
{
  const int tileM = blockIdx.x * 256, tileN = blockIdx.y * 256;
  floatx4 acc[8][4] = {};
  gemm_core(A, Bt, K, tileM, tileN, acc);

  const int tid = threadIdx.x, wave = tid >> 6, lane = tid & 63;
  const int quad = lane >> 4, l16 = lane & 15;
  const int wm = wave >> 2, wn = wave & 3;

  float bv4[4];
  #pragma unroll
  for (int ni = 0; ni < 4; ni++) bv4[ni] = bias[tileN + wn * 64 + ni * 16 + l16];

  #pragma unroll
  for (int mi = 0; mi < 8; mi++){
    #pragma unroll
    for (int r = 0; r < 4; r++){
      const int row = tileM + wm * 128 + mi * 16 + quad * 4 + r;
      #pragma unroll
      for (int ni = 0; ni < 4; ni++){
        const int col = tileN + wn * 64 + ni * 16 + l16;
        float v = acc[mi][ni][r] + bv4[ni];
        if constexpr (EPI == 0){ v = (v > 0.f) ? (v + 1.f) : expf(v); }
        else if constexpr (EPI == 2){ v = gelu_f(v); }
        else if constexpr (EPI == 3){ v = gelu_f(v) + res[(size_t)row * N + col]; }
        out[(size_t)row * N + col] = f2b(v);
      }
    }
  }
}

// Fused QKV GEMM: Bt = [WqT;WkT;WvT] (3072 x K), same core.
__global__ __launch_bounds__(512, 2)
void qkv_gemm_kernel(const ushort_t* __restrict__ A, const ushort_t* __restrict__ Bt,
                     const float* __restrict__ bq, const float* __restrict__ bk,
                     const float* __restrict__ bv,
                     ushort_t* __restrict__ outQ, ushort_t* __restrict__ outK,
                     ushort_t* __restrict__ outV, int K)
{
  const int tileM = blockIdx.x * 256, tileN = blockIdx.y * 256;
  floatx4 acc[8][4] = {};
  gemm_core(A, Bt, K, tileM, tileN, acc);

  const int tid = threadIdx.x, wave = tid >> 6, lane = tid & 63;
  const int quad = lane >> 4, l16 = lane & 15;
  const int wm = wave >> 2, wn = wave & 3;

  const int seg  = tileN >> 10;                 // 0=Q, 1=K, 2=V
  const int nloc = tileN & 1023;
  const float* bias = (seg == 0) ? bq : (seg == 1) ? bk : bv;
  ushort_t* out     = (seg == 0) ? outQ : (seg == 1) ? outK : outV;

  float bv4[4];
  #pragma unroll
  for (int ni = 0; ni < 4; ni++) bv4[ni] = bias[nloc + wn * 64 + ni * 16 + l16];

  #pragma unroll
  for (int mi = 0; mi < 8; mi++){
    #pragma unroll
    for (int r = 0; r < 4; r++){
      const int row = tileM + wm * 128 + mi * 16 + quad * 4 + r;
      #pragma unroll
      for (int ni = 0; ni < 4; ni++){
        const int col = nloc + wn * 64 + ni * 16 + l16;
        float v = acc[mi][ni][r] + bv4[ni];
        if (seg < 2){ v = (v > 0.f) ? (v + 1.f) : expf(v); }
        out[(size_t)row * 1024 + col] = f2b(v);
      }
    }
  }
}

// KV[b,h] = sum_s K*V; Ksum[b,h] = sum_s K  (bf16 in, fp32 atomics)
__global__ __launch_bounds__(256)
void reduce_kv_kernel(const ushort_t* __restrict__ Kb, const ushort_t* __restrict__ Vb,
                      float* __restrict__ KV, float* __restrict__ Ksum)
{
  const int b = blockIdx.x >> 6, chunk = blockIdx.x & 63;
  const int t = threadIdx.x;
  const size_t base = ((size_t)b*4096 + (size_t)chunk*64)*1024 + t*4;
  float kv[4] = {0,0,0,0}, ks[4] = {0,0,0,0};
  for (int s = 0; s < 64; s++){
    ushort4v kk = *(const ushort4v*)(Kb + base + (size_t)s*1024);
    ushort4v vv = *(const ushort4v*)(Vb + base + (size_t)s*1024);
    #pragma unroll
    for (int j = 0; j < 4; j++){ float kf = b2f(kk[j]); kv[j] += kf*b2f(vv[j]); ks[j] += kf; }
  }
  #pragma unroll
  for (int j = 0; j < 4; j++){
    atomicAdd(&KV[b*1024 + t*4 + j], kv[j]);
    atomicAdd(&Ksum[b*1024 + t*4 + j], ks[j]);
  }
}

// Q <- Q*KV / (Q*Ksum + eps), in place (bf16)
__global__ __launch_bounds__(256)
void attn_map_kernel(ushort_t* __restrict__ Q, const float* __restrict__ KV, const float* __restrict__ Ksum)
{
  const size_t g = (size_t)blockIdx.x*256 + threadIdx.x;
  const size_t base = g*4;
  const int b  = (int)(base >> 22);
  const int h0 = (int)(base & 1023);
  ushort4v q4 = *(const ushort4v*)(Q + base);
  ushort4v o4;
  #pragma unroll
  for (int j = 0; j < 4; j++){
    float q = b2f(q4[j]);
    float v = q*KV[b*1024 + h0 + j] / (q*Ksum[b*1024 + h0 + j] + 1e-6f);
    o4[j] = f2b(v);
  }
  *(ushort4v*)(Q + base) = o4;
}

// LayerNorm rows of 1024: y(bf16) -> xb(bf16) AND xf(fp32)
__global__ __launch_bounds__(256)
void ln_kernel(const ushort_t* __restrict__ y, const float* __restrict__ sc,
               const float* __restrict__ bi, ushort_t* __restrict__ xb, float* __restrict__ xf)
{
  const int row = blockIdx.x, t = threadIdx.x;
  const ushort_t* yr = y + (size_t)row*1024;
  ushort4v v4 = *(const ushort4v*)(yr + t*4);
  float f[4]; float s1 = 0.f, s2 = 0.f;
  #pragma unroll
  for (int j = 0; j < 4; j++){ f[j] = b2f(v4[j]); s1 += f[j]; s2 += f[j]*f[j]; }
  #pragma unroll
  for (int off = 32; off; off >>= 1){ s1 += __shfl_down(s1, off); s2 += __shfl_down(s2, off); }
  __shared__ float red[2][4];
  const int wave = t >> 6, lane = t & 63;
  if (lane == 0){ red[0][wave] = s1; red[1][wave] = s2; }
  __syncthreads();
  s1 = red[0][0] + red[0][1] + red[0][2] + red[0][3];
  s2 = red[1][0] + red[1][1] + red[1][2] + red[1][3];
  const float mean = s1 * (1.0f/1024.0f);
  const float var  = s2 * (1.0f/1024.0f) - mean*mean;
  const float inv  = rsqrtf(var + 1e-6f);
  ushort4v o4;
  #pragma unroll
  for (int j = 0; j < 4; j++){
    const int h = t*4 + j;
    const float o = (f[j] - mean)*inv*sc[h] + bi[h];
    o4[j] = f2b(o);
    xf[(size_t)row*1024 + h] = o;
  }
  *(ushort4v*)(xb + (size_t)row*1024 + t*4) = o4;
}

// ---------------------------------------------------------------------------
// Fused per-block weight transpose+convert: 6 matrices in one dispatch.
// ---------------------------------------------------------------------------
struct TParams { const float* src[6]; ushort_t* dst[6]; };

__global__ __launch_bounds__(256)
void transpose_all_kernel(TParams p)
{
  __shared__ float tile[32][33];
  const int id = blockIdx.x;
  int m, bx, by, R, C;
  if (id < 4096){ m = 4; int l = id;        bx = l & 127; by = l >> 7; R = 1024; C = 4096; }
  else if (id < 8192){ m = 5; int l = id - 4096; bx = l & 31; by = l >> 5; R = 4096; C = 1024; }
  else { int l = id - 8192; m = l >> 10; l &= 1023; bx = l & 31; by = l >> 5; R = 1024; C = 1024; }
  const float* in = p.src[m];
  ushort_t* out = p.dst[m];
  const int t = threadIdx.x;
  const int tx = t & 31, ty = t >> 5;
  const int rb = by*32, cb = bx*32;
  #pragma unroll
  for (int j = 0; j < 32; j += 8) tile[ty+j][tx] = in[(size_t)(rb+ty+j)*C + cb+tx];
  __syncthreads();
  #pragma unroll
  for (int j = 0; j < 32; j += 8) out[(size_t)(cb+ty+j)*R + rb+tx] = f2b(tile[tx][ty+j]);
}

// bf16 copy of fp32 input
__global__ __launch_bounds__(256)
void cvt_kernel(const float* __restrict__ in, ushort_t* __restrict__ out)
{
  const size_t base = ((size_t)blockIdx.x*256 + threadIdx.x)*4;
  ushort4v o4;
  #pragma unroll
  for (int j = 0; j < 4; j++) o4[j] = f2b(in[base + j]);
  *(ushort4v*)(out + base) = o4;
}

extern "C" void kernel_launch(void* const* d_in, const int* in_sizes, int n_in,
                              void* d_out, int out_size, void* d_ws, size_t ws_size,
                              hipStream_t stream)
{
  const float* x_in = (const float*)d_in[0];
  const float* Wq   = (const float*)d_in[1];
  const float* bq   = (const float*)d_in[2];
  const float* Wk   = (const float*)d_in[3];
  const float* bk   = (const float*)d_in[4];
  const float* Wv   = (const float*)d_in[5];
  const float* bv   = (const float*)d_in[6];
  const float* Wo   = (const float*)d_in[7];
  const float* bo   = (const float*)d_in[8];
  const float* ln1s = (const float*)d_in[9];
  const float* ln1b = (const float*)d_in[10];
  const float* W1   = (const float*)d_in[11];
  const float* b1   = (const float*)d_in[12];
  const float* W2   = (const float*)d_in[13];
  const float* b2   = (const float*)d_in[14];
  const float* ln2s = (const float*)d_in[15];
  const float* ln2b = (const float*)d_in[16];

  float* xf = (float*)d_out;            // fp32 master activation (also final output)

  char* ws = (char*)d_ws;
  const size_t MB = 1024*1024;
  ushort_t* xb     = (ushort_t*)(ws);              // 32MB bf16 activation
  char*     regB   = ws + 32*MB;                   // 160MB aliased region
  ushort_t* bufQ   = (ushort_t*)(regB);            // attn: 32MB Q -> V_attn
  ushort_t* bufK   = (ushort_t*)(regB + 32*MB);    // attn: 32MB K
  ushort_t* bufVal = (ushort_t*)(regB + 64*MB);    // attn: 32MB value -> pre-LN y
  ushort_t* bufH   = (ushort_t*)(regB);            // ff:   128MB hidden (stomps Q/K/Val)
  ushort_t* bufY   = (ushort_t*)(regB + 128*MB);   // ff:   32MB pre-LN y
  ushort_t* WqkvT  = (ushort_t*)(ws + 192*MB);     // 6MB [3072][1024]
  ushort_t* WoT    = (ushort_t*)(ws + 198*MB);     // 2MB
  ushort_t* W1T    = (ushort_t*)(ws + 200*MB);     // 8MB [4096][1024]
  ushort_t* W2T    = (ushort_t*)(ws + 208*MB);     // 8MB [1024][4096]
  float*    KV     = (float*)(ws + 216*MB);        // 16KB
  float*    Ksum   = (float*)(ws + 216*MB + 16*1024);

  const int M = 16384, D = 1024, FF = 4096;
  const dim3 blk(256);
  const dim3 blkG(512);

  hipMemcpyAsync(xf, x_in, (size_t)M*D*sizeof(float), hipMemcpyDeviceToDevice, stream);
  cvt_kernel<<<dim3(M*D/1024), blk, 0, stream>>>(x_in, xb);

  for (int i = 0; i < 8; i++){
    TParams tp;
    tp.src[0] = Wq + (size_t)i*D*D;  tp.dst[0] = WqkvT;
    tp.src[1] = Wk + (size_t)i*D*D;  tp.dst[1] = WqkvT + 1024*1024;
    tp.src[2] = Wv + (size_t)i*D*D;  tp.dst[2] = WqkvT + 2*1024*1024;
    tp.src[3] = Wo + (size_t)i*D*D;  tp.dst[3] = WoT;
    tp.src[4] = W1 + (size_t)i*D*FF; tp.dst[4] = W1T;
    tp.src[5] = W2 + (size_t)i*FF*D; tp.dst[5] = W2T;
    transpose_all_kernel<<<dim3(12288), blk, 0, stream>>>(tp);

    // Q = elu(x@Wq+bq)+1 ; K = elu(x@Wk+bk)+1 ; value = x@Wv+bv  (one fused GEMM)
    qkv_gemm_kernel<<<dim3(64, 12), blkG, 0, stream>>>(xb, WqkvT, bq + i*D, bk + i*D, bv + i*D,
                                                       bufQ, bufK, bufVal, D);

    hipMemsetAsync(KV, 0, 32*1024, stream);
    reduce_kv_kernel<<<dim3(256), blk, 0, stream>>>(bufK, bufVal, KV, Ksum);
    attn_map_kernel<<<dim3(16384), blk, 0, stream>>>(bufQ, KV, Ksum);

    // y = gelu(V_attn@Wo + bo) + x ; x = LN1(y)
    gemm_kernel<3><<<dim3(64, 4), blkG, 0, stream>>>(bufQ, WoT, bo + i*D, xf, bufVal, D, D);
    ln_kernel<<<dim3(16384), blk, 0, stream>>>(bufVal, ln1s + i*D, ln1b + i*D, xb, xf);

    // h = gelu(x@W1 + b1) ; y = gelu(h@W2 + b2) + x ; x = LN2(y)   (full M)
    gemm_kernel<2><<<dim3(64, 16), blkG, 0, stream>>>(xb, W1T, b1 + i*FF, nullptr, bufH, FF, D);
    gemm_kernel<3><<<dim3(64, 4),  blkG, 0, stream>>>(bufH, W2T, b2 + i*D, xf, bufY, D, FF);
    ln_kernel<<<dim3(16384), blk, 0, stream>>>(bufY, ln2s + i*D, ln2b + i*D, xb, xf);
  }
  (void)in_sizes; (void)n_in; (void)out_size; (void)ws_size;
}

// Round 6
// 5431.977 us; speedup vs baseline: 1.2139x; 1.2139x over previous
//
#include <hip/hip_runtime.h>
#include <hip/hip_bf16.h>
#include <cstdint>

typedef unsigned short ushort_t;
typedef __attribute__((ext_vector_type(8))) short short8;
typedef __attribute__((ext_vector_type(4))) float floatx4;
typedef __attribute__((ext_vector_type(4))) ushort_t ushort4v;

#define DEVI __device__ __forceinline__

DEVI float b2f(ushort_t u){ union{unsigned int i; float f;} v; v.i = ((unsigned int)u)<<16; return v.f; }
DEVI ushort_t f2b(float f){ union{float f; unsigned int i;} v; v.f=f; unsigned int r = (v.i + 0x7FFFu + ((v.i>>16)&1u)) >> 16; return (ushort_t)r; }

DEVI float gelu_f(float t){
  float t3 = t*t*t;
  return 0.5f*t*(1.0f + tanhf(0.7978845608028654f*(t + 0.044715f*t3)));
}

#define GLD_LDS16(src, dst) \
  __builtin_amdgcn_global_load_lds((const __attribute__((address_space(1))) void*)(src), \
                                   (__attribute__((address_space(3))) void*)(dst), 16, 0, 0)

// raw barrier: does NOT drain vmcnt (unlike __syncthreads); "memory" clobber
// stops the compiler moving LDS/global ops across it.
#define BAR()    asm volatile("s_barrier" ::: "memory")
#define WAITV(n) asm volatile("s_waitcnt vmcnt(" #n ")" ::: "memory")

#define MFMA16(d, a, b) d = __builtin_amdgcn_mfma_f32_16x16x32_bf16(a, b, d, 0, 0, 0)

// ---------------------------------------------------------------------------
// 256x256 tile, BK=64, 8 waves, double-buffered LDS (128 KiB).
// ROUND-6 CHANGE: ONE phase per K-tile — 24 ds_read_b128 then 64 MFMAs, with
// exactly 2 barriers + 1 counted vmcnt per K-tile (was 8-9 barriers/K-tile).
// Rationale: R0/R4/R5 (three different schedules, 8+ sync events per K-tile)
// all pinned at 21-22% MfmaUtil; per-K-tile time ~9.5K cyc vs ~1.2K of actual
// work. Barrier arrival skew at 2 waves/SIMD is the suspected dominant cost
// (m233: 2-phase floor has ~72% stage+vmcnt+barrier overhead). Waves now
// free-run through read+MFMA clusters; cross-wave overlap replaces lockstep.
//
// Per K-tile t (buf = t&1, statically unrolled x2):
//   reads: af/bf for both k-halves (24 ds_read_b128, compiler lgkm waits)
//   64 MFMA (kh0 then kh1 per acc element -> accumulation order unchanged)
//   BAR                      // all waves' reads of buf done
//   STAGE_TILE(t+2 -> buf)   // 8 loads into the just-freed buffer
//   WAITV(8)                 // certifies T(t+1): 8 older drained, 8 newer remain
//   BAR                      // publish certification to all waves
// Lookahead: 2 tiles (16 loads peak in flight per wave); vmcnt never 0
// mid-loop. Tail: WAITV(0) once before the final tile.
// LDS layout + XOR granule swizzle + pre-swizzled global source: unchanged
// (bank conflicts measured 0). Requires nkt even and >= 2 (K=1024/4096 here).
// ---------------------------------------------------------------------------
template<int BUFOFF>
DEVI void ktile2(const ushort_t* aB0, const ushort_t* aB1,
                 const ushort_t* bB0, const ushort_t* bB1, floatx4 (&acc)[8][4])
{
  short8 a0[8], a1[8], b0[4], b1[4];
  #pragma unroll
  for (int mi = 0; mi < 8; mi++) a0[mi] = *(const short8*)(aB0 + BUFOFF + mi*1024);
  #pragma unroll
  for (int ni = 0; ni < 4; ni++) b0[ni] = *(const short8*)(bB0 + BUFOFF + ni*1024);
  #pragma unroll
  for (int mi = 0; mi < 8; mi++) a1[mi] = *(const short8*)(aB1 + BUFOFF + mi*1024);
  #pragma unroll
  for (int ni = 0; ni < 4; ni++) b1[ni] = *(const short8*)(bB1 + BUFOFF + ni*1024);
  #pragma unroll
  for (int ni = 0; ni < 4; ni++)
    #pragma unroll
    for (int mi = 0; mi < 8; mi++) MFMA16(acc[mi][ni], a0[mi], b0[ni]);
  #pragma unroll
  for (int ni = 0; ni < 4; ni++)
    #pragma unroll
    for (int mi = 0; mi < 8; mi++) MFMA16(acc[mi][ni], a1[mi], b1[ni]);
}

DEVI void gemm_core(const ushort_t* __restrict__ A, const ushort_t* __restrict__ Bt,
                    int K, int tileM, int tileN, floatx4 (&acc)[8][4])
{
  __shared__ alignas(16) ushort_t As[2][16384];
  __shared__ alignas(16) ushort_t Bs[2][16384];
  const int tid  = threadIdx.x;
  const int wave = tid >> 6, lane = tid & 63;
  const int quad = lane >> 4, l16 = lane & 15;
  const int wm = wave >> 2, wn = wave & 3;          // 2 x 4 wave grid, 128x64 out each

  // staging: thread c handles row rr=c>>3, stored granule gg=(c&7)^(rr&7)
  // (inverse of the read-side swizzle; global source pre-swizzled)
  const int rr = tid >> 3;
  const int gg = (tid & 7) ^ (rr & 7);
  const ushort_t* srcA = A  + (size_t)(tileM + rr) * K + gg * 8;
  const ushort_t* srcB = Bt + (size_t)(tileN + rr) * K + gg * 8;
  const size_t K64 = (size_t)K * 64;
  ushort_t* dstA = &As[0][0] + wave * 512;
  ushort_t* dstB = &Bs[0][0] + wave * 512;

  // full K-tile stage: rows rr, rr+64, rr+128, rr+192 of A and B (8 loads/wave)
#define STAGE_TILE(t, BO) do{ \
    const size_t ko = (size_t)(t) * 64; \
    GLD_LDS16(srcA + ko,          dstA + (BO)); \
    GLD_LDS16(srcA + ko + K64,    dstA + (BO) + 4096); \
    GLD_LDS16(srcA + ko + 2*K64,  dstA + (BO) + 8192); \
    GLD_LDS16(srcA + ko + 3*K64,  dstA + (BO) + 12288); \
    GLD_LDS16(srcB + ko,          dstB + (BO)); \
    GLD_LDS16(srcB + ko + K64,    dstB + (BO) + 4096); \
    GLD_LDS16(srcB + ko + 2*K64,  dstB + (BO) + 8192); \
    GLD_LDS16(srcB + ko + 3*K64,  dstB + (BO) + 12288); \
  }while(0)

  // frag-read bases: slot swizzle s0 (k-half 0) and s0^32 (k-half 1)
  const int s0 = (quad ^ (l16 & 7)) * 8;
  const int s1 = s0 ^ 32;
  const ushort_t* aB0 = &As[0][0] + (wm*128 + l16)*64 + s0;
  const ushort_t* aB1 = &As[0][0] + (wm*128 + l16)*64 + s1;
  const ushort_t* bB0 = &Bs[0][0] + (wn*64  + l16)*64 + s0;
  const ushort_t* bB1 = &Bs[0][0] + (wn*64  + l16)*64 + s1;

  const int nkt = K >> 6;   // even, >= 2 for all K used here (16 or 64)

  // prologue: T0 -> buf0, T1 -> buf1; certify T0 (T1's 8 loads stay in flight)
  STAGE_TILE(0, 0);
  STAGE_TILE(1, 16384);
  WAITV(8);
  BAR();

  for (int tt = 0; tt < nkt; tt += 2){
    // ---- tile tt (buf0)
    ktile2<0>(aB0, aB1, bB0, bB1, acc);
    BAR();                                   // all waves done reading buf0
    if (tt + 2 < nkt){ STAGE_TILE(tt + 2, 0); WAITV(8); }   // certify T(tt+1)
    else             { WAITV(0); }                           // tail: drain last
    BAR();                                   // publish certification
    // ---- tile tt+1 (buf1)
    ktile2<16384>(aB0, aB1, bB0, bB1, acc);
    if (tt + 3 < nkt){
      BAR();
      STAGE_TILE(tt + 3, 16384); WAITV(8);   // certify T(tt+2)
      BAR();
    } else if (tt + 2 < nkt){
      BAR(); WAITV(0); BAR();                // certify final tile T(tt+2)
    }
    // else: last tile consumed, fall out
  }
#undef STAGE_TILE
}

// out[M,N](bf16) = epi(A[M,K](bf16) @ Bt[N,K]^T + bias(fp32) [, res(fp32)])
// EPI: 0 = elu(v)+1, 1 = v, 2 = gelu(v), 3 = gelu(v)+res
template<int EPI>
__global__ __launch_bounds__(512, 2)
void gemm_kernel(const ushort_t* __restrict__ A, const ushort_t* __restrict__ Bt,
                 const float* __restrict__ bias, const float* __restrict__ res,
                 ushort_t* __restrict__ out, int N, int K)
{
  const int tileM = blockIdx.x * 256, tileN = blockIdx.y * 256;
  floatx4 acc[8][4] = {};
  gemm_core(A, Bt, K, tileM, tileN, acc);

  const int tid = threadIdx.x, wave = tid >> 6, lane = tid & 63;
  const int quad = lane >> 4, l16 = lane & 15;
  const int wm = wave >> 2, wn = wave & 3;

  float bv4[4];
  #pragma unroll
  for (int ni = 0; ni < 4; ni++) bv4[ni] = bias[tileN + wn * 64 + ni * 16 + l16];

  #pragma unroll
  for (int mi = 0; mi < 8; mi++){
    #pragma unroll
    for (int r = 0; r < 4; r++){
      const int row = tileM + wm * 128 + mi * 16 + quad * 4 + r;
      #pragma unroll
      for (int ni = 0; ni < 4; ni++){
        const int col = tileN + wn * 64 + ni * 16 + l16;
        float v = acc[mi][ni][r] + bv4[ni];
        if constexpr (EPI == 0){ v = (v > 0.f) ? (v + 1.f) : expf(v); }
        else if constexpr (EPI == 2){ v = gelu_f(v); }
        else if constexpr (EPI == 3){ v = gelu_f(v) + res[(size_t)row * N + col]; }
        out[(size_t)row * N + col] = f2b(v);
      }
    }
  }
}

// Fused QKV GEMM: Bt = [WqT;WkT;WvT] (3072 x K), same core.
__global__ __launch_bounds__(512, 2)
void qkv_gemm_kernel(const ushort_t* __restrict__ A, const ushort_t* __restrict__ Bt,
                     const float* __restrict__ bq, const float* __restrict__ bk,
                     const float* __restrict__ bv,
                     ushort_t* __restrict__ outQ, ushort_t* __restrict__ outK,
                     ushort_t* __restrict__ outV, int K)
{
  const int tileM = blockIdx.x * 256, tileN = blockIdx.y * 256;
  floatx4 acc[8][4] = {};
  gemm_core(A, Bt, K, tileM, tileN, acc);

  const int tid = threadIdx.x, wave = tid >> 6, lane = tid & 63;
  const int quad = lane >> 4, l16 = lane & 15;
  const int wm = wave >> 2, wn = wave & 3;

  const int seg  = tileN >> 10;                 // 0=Q, 1=K, 2=V
  const int nloc = tileN & 1023;
  const float* bias = (seg == 0) ? bq : (seg == 1) ? bk : bv;
  ushort_t* out     = (seg == 0) ? outQ : (seg == 1) ? outK : outV;

  float bv4[4];
  #pragma unroll
  for (int ni = 0; ni < 4; ni++) bv4[ni] = bias[nloc + wn * 64 + ni * 16 + l16];

  #pragma unroll
  for (int mi = 0; mi < 8; mi++){
    #pragma unroll
    for (int r = 0; r < 4; r++){
      const int row = tileM + wm * 128 + mi * 16 + quad * 4 + r;
      #pragma unroll
      for (int ni = 0; ni < 4; ni++){
        const int col = nloc + wn * 64 + ni * 16 + l16;
        float v = acc[mi][ni][r] + bv4[ni];
        if (seg < 2){ v = (v > 0.f) ? (v + 1.f) : expf(v); }
        out[(size_t)row * 1024 + col] = f2b(v);
      }
    }
  }
}

// KV[b,h] = sum_s K*V; Ksum[b,h] = sum_s K  (bf16 in, fp32 atomics)
__global__ __launch_bounds__(256)
void reduce_kv_kernel(const ushort_t* __restrict__ Kb, const ushort_t* __restrict__ Vb,
                      float* __restrict__ KV, float* __restrict__ Ksum)
{
  const int b = blockIdx.x >> 6, chunk = blockIdx.x & 63;
  const int t = threadIdx.x;
  const size_t base = ((size_t)b*4096 + (size_t)chunk*64)*1024 + t*4;
  float kv[4] = {0,0,0,0}, ks[4] = {0,0,0,0};
  for (int s = 0; s < 64; s++){
    ushort4v kk = *(const ushort4v*)(Kb + base + (size_t)s*1024);
    ushort4v vv = *(const ushort4v*)(Vb + base + (size_t)s*1024);
    #pragma unroll
    for (int j = 0; j < 4; j++){ float kf = b2f(kk[j]); kv[j] += kf*b2f(vv[j]); ks[j] += kf; }
  }
  #pragma unroll
  for (int j = 0; j < 4; j++){
    atomicAdd(&KV[b*1024 + t*4 + j], kv[j]);
    atomicAdd(&Ksum[b*1024 + t*4 + j], ks[j]);
  }
}

// Q <- Q*KV / (Q*Ksum + eps), in place (bf16)
__global__ __launch_bounds__(256)
void attn_map_kernel(ushort_t* __restrict__ Q, const float* __restrict__ KV, const float* __restrict__ Ksum)
{
  const size_t g = (size_t)blockIdx.x*256 + threadIdx.x;
  const size_t base = g*4;
  const int b  = (int)(base >> 22);
  const int h0 = (int)(base & 1023);
  ushort4v q4 = *(const ushort4v*)(Q + base);
  ushort4v o4;
  #pragma unroll
  for (int j = 0; j < 4; j++){
    float q = b2f(q4[j]);
    float v = q*KV[b*1024 + h0 + j] / (q*Ksum[b*1024 + h0 + j] + 1e-6f);
    o4[j] = f2b(v);
  }
  *(ushort4v*)(Q + base) = o4;
}

// LayerNorm rows of 1024: y(bf16) -> xb(bf16) AND xf(fp32)
__global__ __launch_bounds__(256)
void ln_kernel(const ushort_t* __restrict__ y, const float* __restrict__ sc,
               const float* __restrict__ bi, ushort_t* __restrict__ xb, float* __restrict__ xf)
{
  const int row = blockIdx.x, t = threadIdx.x;
  const ushort_t* yr = y + (size_t)row*1024;
  ushort4v v4 = *(const ushort4v*)(yr + t*4);
  float f[4]; float s1 = 0.f, s2 = 0.f;
  #pragma unroll
  for (int j = 0; j < 4; j++){ f[j] = b2f(v4[j]); s1 += f[j]; s2 += f[j]*f[j]; }
  #pragma unroll
  for (int off = 32; off; off >>= 1){ s1 += __shfl_down(s1, off); s2 += __shfl_down(s2, off); }
  __shared__ float red[2][4];
  const int wave = t >> 6, lane = t & 63;
  if (lane == 0){ red[0][wave] = s1; red[1][wave] = s2; }
  __syncthreads();
  s1 = red[0][0] + red[0][1] + red[0][2] + red[0][3];
  s2 = red[1][0] + red[1][1] + red[1][2] + red[1][3];
  const float mean = s1 * (1.0f/1024.0f);
  const float var  = s2 * (1.0f/1024.0f) - mean*mean;
  const float inv  = rsqrtf(var + 1e-6f);
  ushort4v o4;
  #pragma unroll
  for (int j = 0; j < 4; j++){
    const int h = t*4 + j;
    const float o = (f[j] - mean)*inv*sc[h] + bi[h];
    o4[j] = f2b(o);
    xf[(size_t)row*1024 + h] = o;
  }
  *(ushort4v*)(xb + (size_t)row*1024 + t*4) = o4;
}

// ---------------------------------------------------------------------------
// Fused per-block weight transpose+convert: 6 matrices in one dispatch.
// ---------------------------------------------------------------------------
struct TParams { const float* src[6]; ushort_t* dst[6]; };

__global__ __launch_bounds__(256)
void transpose_all_kernel(TParams p)
{
  __shared__ float tile[32][33];
  const int id = blockIdx.x;
  int m, bx, by, R, C;
  if (id < 4096){ m = 4; int l = id;        bx = l & 127; by = l >> 7; R = 1024; C = 4096; }
  else if (id < 8192){ m = 5; int l = id - 4096; bx = l & 31; by = l >> 5; R = 4096; C = 1024; }
  else { int l = id - 8192; m = l >> 10; l &= 1023; bx = l & 31; by = l >> 5; R = 1024; C = 1024; }
  const float* in = p.src[m];
  ushort_t* out = p.dst[m];
  const int t = threadIdx.x;
  const int tx = t & 31, ty = t >> 5;
  const int rb = by*32, cb = bx*32;
  #pragma unroll
  for (int j = 0; j < 32; j += 8) tile[ty+j][tx] = in[(size_t)(rb+ty+j)*C + cb+tx];
  __syncthreads();
  #pragma unroll
  for (int j = 0; j < 32; j += 8) out[(size_t)(cb+ty+j)*R + rb+tx] = f2b(tile[tx][ty+j]);
}

// bf16 copy of fp32 input
__global__ __launch_bounds__(256)
void cvt_kernel(const float* __restrict__ in, ushort_t* __restrict__ out)
{
  const size_t base = ((size_t)blockIdx.x*256 + threadIdx.x)*4;
  ushort4v o4;
  #pragma unroll
  for (int j = 0; j < 4; j++) o4[j] = f2b(in[base + j]);
  *(ushort4v*)(out + base) = o4;
}

extern "C" void kernel_launch(void* const* d_in, const int* in_sizes, int n_in,
                              void* d_out, int out_size, void* d_ws, size_t ws_size,
                              hipStream_t stream)
{
  const float* x_in = (const float*)d_in[0];
  const float* Wq   = (const float*)d_in[1];
  const float* bq   = (const float*)d_in[2];
  const float* Wk   = (const float*)d_in[3];
  const float* bk   = (const float*)d_in[4];
  const float* Wv   = (const float*)d_in[5];
  const float* bv   = (const float*)d_in[6];
  const float* Wo   = (const float*)d_in[7];
  const float* bo   = (const float*)d_in[8];
  const float* ln1s = (const float*)d_in[9];
  const float* ln1b = (const float*)d_in[10];
  const float* W1   = (const float*)d_in[11];
  const float* b1   = (const float*)d_in[12];
  const float* W2   = (const float*)d_in[13];
  const float* b2   = (const float*)d_in[14];
  const float* ln2s = (const float*)d_in[15];
  const float* ln2b = (const float*)d_in[16];

  float* xf = (float*)d_out;            // fp32 master activation (also final output)

  char* ws = (char*)d_ws;
  const size_t MB = 1024*1024;
  ushort_t* xb     = (ushort_t*)(ws);              // 32MB bf16 activation
  char*     regB   = ws + 32*MB;                   // 160MB aliased region
  ushort_t* bufQ   = (ushort_t*)(regB);            // attn: 32MB Q -> V_attn
  ushort_t* bufK   = (ushort_t*)(regB + 32*MB);    // attn: 32MB K
  ushort_t* bufVal = (ushort_t*)(regB + 64*MB);    // attn: 32MB value -> pre-LN y
  ushort_t* bufH   = (ushort_t*)(regB);            // ff:   128MB hidden (stomps Q/K/Val)
  ushort_t* bufY   = (ushort_t*)(regB + 128*MB);   // ff:   32MB pre-LN y
  ushort_t* WqkvT  = (ushort_t*)(ws + 192*MB);     // 6MB [3072][1024]
  ushort_t* WoT    = (ushort_t*)(ws + 198*MB);     // 2MB
  ushort_t* W1T    = (ushort_t*)(ws + 200*MB);     // 8MB [4096][1024]
  ushort_t* W2T    = (ushort_t*)(ws + 208*MB);     // 8MB [1024][4096]
  float*    KV     = (float*)(ws + 216*MB);        // 16KB
  float*    Ksum   = (float*)(ws + 216*MB + 16*1024);

  const int M = 16384, D = 1024, FF = 4096;
  const dim3 blk(256);
  const dim3 blkG(512);

  hipMemcpyAsync(xf, x_in, (size_t)M*D*sizeof(float), hipMemcpyDeviceToDevice, stream);
  cvt_kernel<<<dim3(M*D/1024), blk, 0, stream>>>(x_in, xb);

  for (int i = 0; i < 8; i++){
    TParams tp;
    tp.src[0] = Wq + (size_t)i*D*D;  tp.dst[0] = WqkvT;
    tp.src[1] = Wk + (size_t)i*D*D;  tp.dst[1] = WqkvT + 1024*1024;
    tp.src[2] = Wv + (size_t)i*D*D;  tp.dst[2] = WqkvT + 2*1024*1024;
    tp.src[3] = Wo + (size_t)i*D*D;  tp.dst[3] = WoT;
    tp.src[4] = W1 + (size_t)i*D*FF; tp.dst[4] = W1T;
    tp.src[5] = W2 + (size_t)i*FF*D; tp.dst[5] = W2T;
    transpose_all_kernel<<<dim3(12288), blk, 0, stream>>>(tp);

    // Q = elu(x@Wq+bq)+1 ; K = elu(x@Wk+bk)+1 ; value = x@Wv+bv  (one fused GEMM)
    qkv_gemm_kernel<<<dim3(64, 12), blkG, 0, stream>>>(xb, WqkvT, bq + i*D, bk + i*D, bv + i*D,
                                                       bufQ, bufK, bufVal, D);

    hipMemsetAsync(KV, 0, 32*1024, stream);
    reduce_kv_kernel<<<dim3(256), blk, 0, stream>>>(bufK, bufVal, KV, Ksum);
    attn_map_kernel<<<dim3(16384), blk, 0, stream>>>(bufQ, KV, Ksum);

    // y = gelu(V_attn@Wo + bo) + x ; x = LN1(y)
    gemm_kernel<3><<<dim3(64, 4), blkG, 0, stream>>>(bufQ, WoT, bo + i*D, xf, bufVal, D, D);
    ln_kernel<<<dim3(16384), blk, 0, stream>>>(bufVal, ln1s + i*D, ln1b + i*D, xb, xf);

    // h = gelu(x@W1 + b1) ; y = gelu(h@W2 + b2) + x ; x = LN2(y)   (full M)
    gemm_kernel<2><<<dim3(64, 16), blkG, 0, stream>>>(xb, W1T, b1 + i*FF, nullptr, bufH, FF, D);
    gemm_kernel<3><<<dim3(64, 4),  blkG, 0, stream>>>(bufH, W2T, b2 + i*D, xf, bufY, D, FF);
    ln_kernel<<<dim3(16384), blk, 0, stream>>>(bufY, ln2s + i*D, ln2b + i*D, xb, xf);
  }
  (void)in_sizes; (void)n_in; (void)out_size; (void)ws_size;
}